// Round 5
// baseline (1870.360 us; speedup 1.0000x reference)
//
#include <hip/hip_runtime.h>
#include <math.h>

// ---------------- utility: stream d_in -> d_ws ----------------

__global__ void copy_kernel(const float4* __restrict__ src, float4* __restrict__ dst, int n4) {
    int tid = blockIdx.x * blockDim.x + threadIdx.x;
    int stride = gridDim.x * blockDim.x;
    for (int i = tid; i < n4; i += stride) dst[i] = src[i];
}

// ---------------- CSR build ----------------

__global__ void deg_kernel(const int* __restrict__ dst, int* __restrict__ cnt, int E) {
    int tid = blockIdx.x * blockDim.x + threadIdx.x;
    int stride = gridDim.x * blockDim.x;
    for (int e = tid; e < E; e += stride) atomicAdd(&cnt[dst[e]], 1);
}

__global__ void dinv_kernel(const int* __restrict__ cnt, float* __restrict__ dinv, int N) {
    int tid = blockIdx.x * blockDim.x + threadIdx.x;
    int stride = gridDim.x * blockDim.x;
    for (int v = tid; v < N; v += stride) dinv[v] = rsqrtf((float)(cnt[v] + 1)); // +1 self loop
}

// exclusive scan of cnt, 1024 elements per 256-thread block
__global__ void scan1_kernel(const int* __restrict__ cnt, int* __restrict__ excl,
                             int* __restrict__ bsum, int N) {
    int t = threadIdx.x;
    int base = blockIdx.x * 1024 + t * 4;
    int a0 = base + 0 < N ? cnt[base + 0] : 0;
    int a1 = base + 1 < N ? cnt[base + 1] : 0;
    int a2 = base + 2 < N ? cnt[base + 2] : 0;
    int a3 = base + 3 < N ? cnt[base + 3] : 0;
    int s = a0 + a1 + a2 + a3;
    int lane = t & 63, w = t >> 6;
    int inc = s;
    for (int off = 1; off < 64; off <<= 1) {
        int v = __shfl_up(inc, off);
        if (lane >= off) inc += v;
    }
    __shared__ int wsum[4];
    if (lane == 63) wsum[w] = inc;
    __syncthreads();
    int woff = 0;
    for (int i = 0; i < w; ++i) woff += wsum[i];
    int ex = woff + inc - s;
    if (base + 0 < N) excl[base + 0] = ex;
    if (base + 1 < N) excl[base + 1] = ex + a0;
    if (base + 2 < N) excl[base + 2] = ex + a0 + a1;
    if (base + 3 < N) excl[base + 3] = ex + a0 + a1 + a2;
    if (t == 255) bsum[blockIdx.x] = woff + inc;
}

__global__ void scan2_kernel(const int* __restrict__ bsum, int* __restrict__ bsum2, int nb) {
    int t = threadIdx.x;
    int s = t < nb ? bsum[t] : 0;
    int lane = t & 63, w = t >> 6;
    int inc = s;
    for (int off = 1; off < 64; off <<= 1) {
        int v = __shfl_up(inc, off);
        if (lane >= off) inc += v;
    }
    __shared__ int wsum[4];
    if (lane == 63) wsum[w] = inc;
    __syncthreads();
    int woff = 0;
    for (int i = 0; i < w; ++i) woff += wsum[i];
    if (t < nb) bsum2[t] = woff + inc - s;
}

__global__ void scan3_kernel(const int* __restrict__ excl, const int* __restrict__ bsum2,
                             int* __restrict__ rowptr, int* __restrict__ cursor, int N, int E) {
    int tid = blockIdx.x * blockDim.x + threadIdx.x;
    int stride = gridDim.x * blockDim.x;
    for (int i = tid; i < N; i += stride) {
        int r = excl[i] + bsum2[i >> 10];
        rowptr[i] = r;
        cursor[i] = r;
    }
    if (tid == 0) rowptr[N] = E;
}

__global__ void bucket_kernel(const int* __restrict__ src, const int* __restrict__ dst,
                              int* __restrict__ cursor, int* __restrict__ esrc, int E) {
    int tid = blockIdx.x * blockDim.x + threadIdx.x;
    int stride = gridDim.x * blockDim.x;
    for (int e = tid; e < E; e += stride) {
        int p = atomicAdd(&cursor[dst[e]], 1);
        esrc[p] = src[e];
    }
}

// ---------------- layer kernels ----------------

// Ap[N,64] = (X[N,128] @ W1) * dinv[row].  Persistent blocks, all operands in d_ws.
template <int K, int C>
__launch_bounds__(256, 4)
__global__ void gemm1_kernel(const float* __restrict__ X, const float* __restrict__ W,
                             const float* __restrict__ dinv, float* __restrict__ out, int N) {
    constexpr int ROWS = 16;
    constexpr int KV = K / 4;
    __shared__ float  Ws[K * C];
    __shared__ float4 Xs[ROWS * KV];
    const float4* W4 = (const float4*)W;
    float4* Ws4 = (float4*)Ws;
    for (int i = threadIdx.x; i < K * C / 4; i += 256) Ws4[i] = W4[i];
    int ntiles = (N + ROWS - 1) / ROWS;
    int c = threadIdx.x & 63, r0 = threadIdx.x >> 6;
    for (int tile_i = blockIdx.x; tile_i < ntiles; tile_i += gridDim.x) {
        int tile = tile_i * ROWS;
        __syncthreads();                       // Ws ready (1st iter) / Xs WAR (later)
        const float4* X4 = (const float4*)(X + (size_t)tile * K);
        bool full = tile + ROWS <= N;
        for (int i = threadIdx.x; i < ROWS * KV; i += 256) {
            float4 v = make_float4(0.f, 0.f, 0.f, 0.f);
            if (full || tile + i / KV < N) v = X4[i];
            Xs[i] = v;
        }
        __syncthreads();
        if (c < C) {
            float acc0 = 0.f, acc1 = 0.f, acc2 = 0.f, acc3 = 0.f;
#pragma unroll
            for (int k4 = 0; k4 < KV; ++k4) {
                int k = 4 * k4;
                float w0 = Ws[(k + 0) * C + c];
                float w1 = Ws[(k + 1) * C + c];
                float w2 = Ws[(k + 2) * C + c];
                float w3 = Ws[(k + 3) * C + c];
                float4 xv;
                xv = Xs[(r0 +  0) * KV + k4];
                acc0 += xv.x * w0 + xv.y * w1 + xv.z * w2 + xv.w * w3;
                xv = Xs[(r0 +  4) * KV + k4];
                acc1 += xv.x * w0 + xv.y * w1 + xv.z * w2 + xv.w * w3;
                xv = Xs[(r0 +  8) * KV + k4];
                acc2 += xv.x * w0 + xv.y * w1 + xv.z * w2 + xv.w * w3;
                xv = Xs[(r0 + 12) * KV + k4];
                acc3 += xv.x * w0 + xv.y * w1 + xv.z * w2 + xv.w * w3;
            }
            int row = tile + r0;
            if (row      < N) out[(size_t)(row     ) * C + c] = acc0 * dinv[row];
            if (row + 4  < N) out[(size_t)(row + 4 ) * C + c] = acc1 * dinv[row + 4];
            if (row + 8  < N) out[(size_t)(row + 8 ) * C + c] = acc2 * dinv[row + 8];
            if (row + 12 < N) out[(size_t)(row + 12) * C + c] = acc3 * dinv[row + 12];
        }
    }
}

// Wave per node: gather Ap rows via CSR, h = relu(dinv*(sum + Ap[v]*dinv) + b1),
// then fused GEMM2 via __shfl broadcast against LDS W2: A2p[v,c] = (h @ W2)[c] * dinv.
__global__ void layer_mid_kernel(const float* __restrict__ Ap, const int* __restrict__ esrc,
                                 const int* __restrict__ rowptr, const float* __restrict__ dinv,
                                 const float* __restrict__ W2, const float* __restrict__ b1,
                                 float* __restrict__ A2p, int N) {
    __shared__ float Ws[64 * 40];
    for (int i = threadIdx.x; i < 64 * 40; i += 256) Ws[i] = W2[i];
    __syncthreads();
    int gtid = blockIdx.x * blockDim.x + threadIdx.x;
    int wave = gtid >> 6, lane = threadIdx.x & 63;
    int nw = (gridDim.x * blockDim.x) >> 6;
    for (int v = wave; v < N; v += nw) {
        int i0 = rowptr[v], i1 = rowptr[v + 1];
        float acc = 0.f;
        for (int base = i0; base < i1; base += 64) {
            int n = min(64, i1 - base);
            int el = (lane < n) ? esrc[base + lane] : 0;
            int j = 0;
            for (; j + 4 <= n; j += 4) {
                int s0 = __shfl(el, j), s1 = __shfl(el, j + 1);
                int s2 = __shfl(el, j + 2), s3 = __shfl(el, j + 3);
                float f0 = Ap[(size_t)s0 * 64 + lane];
                float f1 = Ap[(size_t)s1 * 64 + lane];
                float f2 = Ap[(size_t)s2 * 64 + lane];
                float f3 = Ap[(size_t)s3 * 64 + lane];
                acc += f0; acc += f1; acc += f2; acc += f3;
            }
            for (; j < n; ++j) {
                int s0 = __shfl(el, j);
                acc += Ap[(size_t)s0 * 64 + lane];
            }
        }
        float dv = dinv[v];
        float h = dv * (acc + Ap[(size_t)v * 64 + lane] * dv) + b1[lane];
        h = h > 0.f ? h : 0.f;
        float a2 = 0.f;
#pragma unroll 8
        for (int k = 0; k < 64; ++k) {
            float hk = __shfl(h, k);
            if (lane < 40) a2 += hk * Ws[k * 40 + lane];
        }
        if (lane < 40) A2p[(size_t)v * 40 + lane] = a2 * dv;
    }
}

// Wave per node: gather A2p rows, z = dinv*(sum + A2p[v]*dinv) + b2,
// out = log_softmax(softmax(z)) over 40 cols.
__global__ void layer_out_kernel(const float* __restrict__ A2p, const int* __restrict__ esrc,
                                 const int* __restrict__ rowptr, const float* __restrict__ dinv,
                                 const float* __restrict__ b2, float* __restrict__ out, int N) {
    int gtid = blockIdx.x * blockDim.x + threadIdx.x;
    int wave = gtid >> 6, lane = threadIdx.x & 63;
    int nw = (gridDim.x * blockDim.x) >> 6;
    for (int v = wave; v < N; v += nw) {
        int i0 = rowptr[v], i1 = rowptr[v + 1];
        bool act = lane < 40;
        float acc = 0.f;
        for (int base = i0; base < i1; base += 64) {
            int n = min(64, i1 - base);
            int el = (lane < n) ? esrc[base + lane] : 0;
            int j = 0;
            for (; j + 4 <= n; j += 4) {
                int s0 = __shfl(el, j), s1 = __shfl(el, j + 1);
                int s2 = __shfl(el, j + 2), s3 = __shfl(el, j + 3);
                if (act) {
                    float f0 = A2p[(size_t)s0 * 40 + lane];
                    float f1 = A2p[(size_t)s1 * 40 + lane];
                    float f2 = A2p[(size_t)s2 * 40 + lane];
                    float f3 = A2p[(size_t)s3 * 40 + lane];
                    acc += f0; acc += f1; acc += f2; acc += f3;
                }
            }
            for (; j < n; ++j) {
                int s0 = __shfl(el, j);
                if (act) acc += A2p[(size_t)s0 * 40 + lane];
            }
        }
        float dv = dinv[v];
        float z = act ? dv * (acc + A2p[(size_t)v * 40 + lane] * dv) + b2[lane] : -INFINITY;
        float m = z;
        for (int off = 32; off; off >>= 1) m = fmaxf(m, __shfl_xor(m, off));
        float e = act ? expf(z - m) : 0.f;
        float s = e;
        for (int off = 32; off; off >>= 1) s += __shfl_xor(s, off);
        float p = e / s;
        float m2 = act ? p : -INFINITY;
        for (int off = 32; off; off >>= 1) m2 = fmaxf(m2, __shfl_xor(m2, off));
        float e2 = act ? expf(p - m2) : 0.f;
        float s2 = e2;
        for (int off = 32; off; off >>= 1) s2 += __shfl_xor(s2, off);
        if (act) out[(size_t)v * 40 + lane] = (p - m2) - logf(s2);
    }
}

// ---------------- launch ----------------

extern "C" void kernel_launch(void* const* d_in, const int* in_sizes, int n_in,
                              void* d_out, int out_size, void* d_ws, size_t ws_size,
                              hipStream_t stream) {
    const float* x_in  = (const float*)d_in[0];
    const int*   ei    = (const int*)d_in[1];
    const float* W1_in = (const float*)d_in[2];
    const float* b1_in = (const float*)d_in[3];
    const float* W2_in = (const float*)d_in[4];
    const float* b2_in = (const float*)d_in[5];
    float* out = (float*)d_out;

    int N = in_sizes[0] / 128;
    int E = in_sizes[1] / 2;
    const int* src = ei;
    const int* dst = ei + E;

    int nb = (N + 1023) / 1024;

    char* ws = (char*)d_ws;
    size_t o = 0;
    auto alloc = [&](size_t bytes) { void* p = ws + o; o += (bytes + 255) & ~(size_t)255; return p; };
    int*   cnt    = (int*)alloc((size_t)N * 4);
    int*   cursor = (int*)alloc((size_t)N * 4);
    float* dinv   = (float*)alloc((size_t)N * 4);
    int*   excl   = (int*)alloc((size_t)N * 4);
    int*   rowptr = (int*)alloc(((size_t)N + 1) * 4);
    int*   bsum   = (int*)alloc(1024);
    int*   bsum2  = (int*)alloc(1024);
    int*   esrc   = (int*)alloc((size_t)E * 4);
    float* Ap     = (float*)alloc((size_t)N * 64 * 4);
    float* A2p    = (float*)alloc((size_t)N * 40 * 4);
    // staged copies of the fp32 inputs (experiment: move all fp32 reads off d_in)
    float* Xc  = (float*)alloc((size_t)N * 128 * 4);
    float* W1c = (float*)alloc(128 * 64 * 4);
    float* W2c = (float*)alloc(64 * 40 * 4);
    float* b1c = (float*)alloc(64 * 4);
    float* b2c = (float*)alloc(40 * 4);

    // stage fp32 inputs into workspace (pure streaming float4 copies)
    copy_kernel<<<2048, 256, 0, stream>>>((const float4*)x_in, (float4*)Xc, N * 128 / 4);
    copy_kernel<<<8, 256, 0, stream>>>((const float4*)W1_in, (float4*)W1c, 128 * 64 / 4);
    copy_kernel<<<4, 256, 0, stream>>>((const float4*)W2_in, (float4*)W2c, 64 * 40 / 4);
    copy_kernel<<<1, 64, 0, stream>>>((const float4*)b1_in, (float4*)b1c, 16);
    copy_kernel<<<1, 64, 0, stream>>>((const float4*)b2_in, (float4*)b2c, 10);

    // CSR build + degree norm
    hipMemsetAsync(cnt, 0, (size_t)N * 4, stream);
    deg_kernel<<<1024, 256, 0, stream>>>(dst, cnt, E);
    dinv_kernel<<<(N + 255) / 256, 256, 0, stream>>>(cnt, dinv, N);
    scan1_kernel<<<nb, 256, 0, stream>>>(cnt, excl, bsum, N);
    scan2_kernel<<<1, 256, 0, stream>>>(bsum, bsum2, nb);
    scan3_kernel<<<(N + 255) / 256, 256, 0, stream>>>(excl, bsum2, rowptr, cursor, N, E);
    bucket_kernel<<<2048, 256, 0, stream>>>(src, dst, cursor, esrc, E);

    // layer 1 linear (scaled): Ap = (Xc @ W1) * dinv   — reads only d_ws
    gemm1_kernel<128, 64><<<1024, 256, 0, stream>>>(Xc, W1c, dinv, Ap, N);
    // gather + relu + fused GEMM2 (scaled)
    layer_mid_kernel<<<2048, 256, 0, stream>>>(Ap, esrc, rowptr, dinv, W2c, b1c, A2p, N);
    // gather + bias + softmax + log_softmax
    layer_out_kernel<<<2048, 256, 0, stream>>>(A2p, esrc, rowptr, dinv, b2c, out, N);
}

// Round 6
// 588.160 us; speedup vs baseline: 3.1800x; 3.1800x over previous
//
#include <hip/hip_runtime.h>
#include <math.h>

// ---------------- utility: stream d_in -> d_ws ----------------

__global__ void copy_kernel(const float4* __restrict__ src, float4* __restrict__ dst, int n4) {
    int tid = blockIdx.x * blockDim.x + threadIdx.x;
    int stride = gridDim.x * blockDim.x;
    for (int i = tid; i < n4; i += stride) dst[i] = src[i];
}

// ---------------- CSR build ----------------

__global__ void deg_kernel(const int* __restrict__ dst, int* __restrict__ cnt, int E) {
    int tid = blockIdx.x * blockDim.x + threadIdx.x;
    int stride = gridDim.x * blockDim.x;
    for (int e = tid; e < E; e += stride) atomicAdd(&cnt[dst[e]], 1);
}

__global__ void dinv_kernel(const int* __restrict__ cnt, float* __restrict__ dinv, int N) {
    int tid = blockIdx.x * blockDim.x + threadIdx.x;
    int stride = gridDim.x * blockDim.x;
    for (int v = tid; v < N; v += stride) dinv[v] = rsqrtf((float)(cnt[v] + 1)); // +1 self loop
}

// exclusive scan of cnt, 1024 elements per 256-thread block
__global__ void scan1_kernel(const int* __restrict__ cnt, int* __restrict__ excl,
                             int* __restrict__ bsum, int N) {
    int t = threadIdx.x;
    int base = blockIdx.x * 1024 + t * 4;
    int a0 = base + 0 < N ? cnt[base + 0] : 0;
    int a1 = base + 1 < N ? cnt[base + 1] : 0;
    int a2 = base + 2 < N ? cnt[base + 2] : 0;
    int a3 = base + 3 < N ? cnt[base + 3] : 0;
    int s = a0 + a1 + a2 + a3;
    int lane = t & 63, w = t >> 6;
    int inc = s;
    for (int off = 1; off < 64; off <<= 1) {
        int v = __shfl_up(inc, off);
        if (lane >= off) inc += v;
    }
    __shared__ int wsum[4];
    if (lane == 63) wsum[w] = inc;
    __syncthreads();
    int woff = 0;
    for (int i = 0; i < w; ++i) woff += wsum[i];
    int ex = woff + inc - s;
    if (base + 0 < N) excl[base + 0] = ex;
    if (base + 1 < N) excl[base + 1] = ex + a0;
    if (base + 2 < N) excl[base + 2] = ex + a0 + a1;
    if (base + 3 < N) excl[base + 3] = ex + a0 + a1 + a2;
    if (t == 255) bsum[blockIdx.x] = woff + inc;
}

__global__ void scan2_kernel(const int* __restrict__ bsum, int* __restrict__ bsum2, int nb) {
    int t = threadIdx.x;
    int s = t < nb ? bsum[t] : 0;
    int lane = t & 63, w = t >> 6;
    int inc = s;
    for (int off = 1; off < 64; off <<= 1) {
        int v = __shfl_up(inc, off);
        if (lane >= off) inc += v;
    }
    __shared__ int wsum[4];
    if (lane == 63) wsum[w] = inc;
    __syncthreads();
    int woff = 0;
    for (int i = 0; i < w; ++i) woff += wsum[i];
    if (t < nb) bsum2[t] = woff + inc - s;
}

__global__ void scan3_kernel(const int* __restrict__ excl, const int* __restrict__ bsum2,
                             int* __restrict__ rowptr, int* __restrict__ cursor, int N, int E) {
    int tid = blockIdx.x * blockDim.x + threadIdx.x;
    int stride = gridDim.x * blockDim.x;
    for (int i = tid; i < N; i += stride) {
        int r = excl[i] + bsum2[i >> 10];
        rowptr[i] = r;
        cursor[i] = r;
    }
    if (tid == 0) rowptr[N] = E;
}

__global__ void bucket_kernel(const int* __restrict__ src, const int* __restrict__ dst,
                              int* __restrict__ cursor, int* __restrict__ esrc, int E) {
    int tid = blockIdx.x * blockDim.x + threadIdx.x;
    int stride = gridDim.x * blockDim.x;
    for (int e = tid; e < E; e += stride) {
        int p = atomicAdd(&cursor[dst[e]], 1);
        esrc[p] = src[e];
    }
}

// ---------------- layer kernels ----------------

// Ap[N,64] = (X[N,128] @ W1) * dinv[row].
// Wave per row (layer_mid-proven structure): lane loads float2 of the row
// (coalesced 512B/wave), 64 double-shfl broadcasts against LDS-resident W1,
// one barrier total, no tile staging.
__global__ void rowgemm_kernel(const float* __restrict__ X, const float* __restrict__ W,
                               const float* __restrict__ dinv, float* __restrict__ Ap, int N) {
    __shared__ float Ws[128 * 64];
    const float4* W4 = (const float4*)W;
    float4* Ws4 = (float4*)Ws;
    for (int i = threadIdx.x; i < 128 * 64 / 4; i += blockDim.x) Ws4[i] = W4[i];
    __syncthreads();
    int gtid = blockIdx.x * blockDim.x + threadIdx.x;
    int wave = gtid >> 6, lane = threadIdx.x & 63;
    int nw = (gridDim.x * blockDim.x) >> 6;
    for (int v = wave; v < N; v += nw) {
        float2 x2 = *(const float2*)(X + (size_t)v * 128 + lane * 2);
        float acc = 0.f;
#pragma unroll 8
        for (int k = 0; k < 64; ++k) {
            float xa = __shfl(x2.x, k);
            float xb = __shfl(x2.y, k);
            acc += xa * Ws[(2 * k) * 64 + lane] + xb * Ws[(2 * k + 1) * 64 + lane];
        }
        Ap[(size_t)v * 64 + lane] = acc * dinv[v];
    }
}

// Wave per node: gather Ap rows via CSR, h = relu(dinv*(sum + Ap[v]*dinv) + b1),
// then fused GEMM2 via __shfl broadcast against LDS W2: A2p[v,c] = (h @ W2)[c] * dinv.
__global__ void layer_mid_kernel(const float* __restrict__ Ap, const int* __restrict__ esrc,
                                 const int* __restrict__ rowptr, const float* __restrict__ dinv,
                                 const float* __restrict__ W2, const float* __restrict__ b1,
                                 float* __restrict__ A2p, int N) {
    __shared__ float Ws[64 * 40];
    for (int i = threadIdx.x; i < 64 * 40; i += 256) Ws[i] = W2[i];
    __syncthreads();
    int gtid = blockIdx.x * blockDim.x + threadIdx.x;
    int wave = gtid >> 6, lane = threadIdx.x & 63;
    int nw = (gridDim.x * blockDim.x) >> 6;
    for (int v = wave; v < N; v += nw) {
        int i0 = rowptr[v], i1 = rowptr[v + 1];
        float acc = 0.f;
        for (int base = i0; base < i1; base += 64) {
            int n = min(64, i1 - base);
            int el = (lane < n) ? esrc[base + lane] : 0;
            int j = 0;
            for (; j + 4 <= n; j += 4) {
                int s0 = __shfl(el, j), s1 = __shfl(el, j + 1);
                int s2 = __shfl(el, j + 2), s3 = __shfl(el, j + 3);
                float f0 = Ap[(size_t)s0 * 64 + lane];
                float f1 = Ap[(size_t)s1 * 64 + lane];
                float f2 = Ap[(size_t)s2 * 64 + lane];
                float f3 = Ap[(size_t)s3 * 64 + lane];
                acc += f0; acc += f1; acc += f2; acc += f3;
            }
            for (; j < n; ++j) {
                int s0 = __shfl(el, j);
                acc += Ap[(size_t)s0 * 64 + lane];
            }
        }
        float dv = dinv[v];
        float h = dv * (acc + Ap[(size_t)v * 64 + lane] * dv) + b1[lane];
        h = h > 0.f ? h : 0.f;
        float a2 = 0.f;
#pragma unroll 8
        for (int k = 0; k < 64; ++k) {
            float hk = __shfl(h, k);
            if (lane < 40) a2 += hk * Ws[k * 40 + lane];
        }
        if (lane < 40) A2p[(size_t)v * 40 + lane] = a2 * dv;
    }
}

// Wave per node: gather A2p rows, z = dinv*(sum + A2p[v]*dinv) + b2,
// out = log_softmax(softmax(z)) over 40 cols.
__global__ void layer_out_kernel(const float* __restrict__ A2p, const int* __restrict__ esrc,
                                 const int* __restrict__ rowptr, const float* __restrict__ dinv,
                                 const float* __restrict__ b2, float* __restrict__ out, int N) {
    int gtid = blockIdx.x * blockDim.x + threadIdx.x;
    int wave = gtid >> 6, lane = threadIdx.x & 63;
    int nw = (gridDim.x * blockDim.x) >> 6;
    for (int v = wave; v < N; v += nw) {
        int i0 = rowptr[v], i1 = rowptr[v + 1];
        bool act = lane < 40;
        float acc = 0.f;
        for (int base = i0; base < i1; base += 64) {
            int n = min(64, i1 - base);
            int el = (lane < n) ? esrc[base + lane] : 0;
            int j = 0;
            for (; j + 4 <= n; j += 4) {
                int s0 = __shfl(el, j), s1 = __shfl(el, j + 1);
                int s2 = __shfl(el, j + 2), s3 = __shfl(el, j + 3);
                if (act) {
                    float f0 = A2p[(size_t)s0 * 40 + lane];
                    float f1 = A2p[(size_t)s1 * 40 + lane];
                    float f2 = A2p[(size_t)s2 * 40 + lane];
                    float f3 = A2p[(size_t)s3 * 40 + lane];
                    acc += f0; acc += f1; acc += f2; acc += f3;
                }
            }
            for (; j < n; ++j) {
                int s0 = __shfl(el, j);
                if (act) acc += A2p[(size_t)s0 * 40 + lane];
            }
        }
        float dv = dinv[v];
        float z = act ? dv * (acc + A2p[(size_t)v * 40 + lane] * dv) + b2[lane] : -INFINITY;
        float m = z;
        for (int off = 32; off; off >>= 1) m = fmaxf(m, __shfl_xor(m, off));
        float e = act ? expf(z - m) : 0.f;
        float s = e;
        for (int off = 32; off; off >>= 1) s += __shfl_xor(s, off);
        float p = e / s;
        float m2 = act ? p : -INFINITY;
        for (int off = 32; off; off >>= 1) m2 = fmaxf(m2, __shfl_xor(m2, off));
        float e2 = act ? expf(p - m2) : 0.f;
        float s2 = e2;
        for (int off = 32; off; off >>= 1) s2 += __shfl_xor(s2, off);
        if (act) out[(size_t)v * 40 + lane] = (p - m2) - logf(s2);
    }
}

// ---------------- launch ----------------

extern "C" void kernel_launch(void* const* d_in, const int* in_sizes, int n_in,
                              void* d_out, int out_size, void* d_ws, size_t ws_size,
                              hipStream_t stream) {
    const float* x_in  = (const float*)d_in[0];
    const int*   ei    = (const int*)d_in[1];
    const float* W1_in = (const float*)d_in[2];
    const float* b1_in = (const float*)d_in[3];
    const float* W2_in = (const float*)d_in[4];
    const float* b2_in = (const float*)d_in[5];
    float* out = (float*)d_out;

    int N = in_sizes[0] / 128;
    int E = in_sizes[1] / 2;
    const int* src = ei;
    const int* dst = ei + E;

    int nb = (N + 1023) / 1024;

    char* ws = (char*)d_ws;
    size_t o = 0;
    auto alloc = [&](size_t bytes) { void* p = ws + o; o += (bytes + 255) & ~(size_t)255; return p; };
    int*   cnt    = (int*)alloc((size_t)N * 4);
    int*   cursor = (int*)alloc((size_t)N * 4);
    float* dinv   = (float*)alloc((size_t)N * 4);
    int*   excl   = (int*)alloc((size_t)N * 4);
    int*   rowptr = (int*)alloc(((size_t)N + 1) * 4);
    int*   bsum   = (int*)alloc(1024);
    int*   bsum2  = (int*)alloc(1024);
    int*   esrc   = (int*)alloc((size_t)E * 4);
    float* Ap     = (float*)alloc((size_t)N * 64 * 4);
    float* A2p    = (float*)alloc((size_t)N * 40 * 4);
    float* W1c = (float*)alloc(128 * 64 * 4);
    float* W2c = (float*)alloc(64 * 40 * 4);
    float* b1c = (float*)alloc(64 * 4);
    float* b2c = (float*)alloc(40 * 4);

    // stage small fp32 params into workspace
    copy_kernel<<<8, 256, 0, stream>>>((const float4*)W1_in, (float4*)W1c, 128 * 64 / 4);
    copy_kernel<<<4, 256, 0, stream>>>((const float4*)W2_in, (float4*)W2c, 64 * 40 / 4);
    copy_kernel<<<1, 64, 0, stream>>>((const float4*)b1_in, (float4*)b1c, 16);
    copy_kernel<<<1, 64, 0, stream>>>((const float4*)b2_in, (float4*)b2c, 10);

    // CSR build + degree norm
    hipMemsetAsync(cnt, 0, (size_t)N * 4, stream);
    deg_kernel<<<1024, 256, 0, stream>>>(dst, cnt, E);
    dinv_kernel<<<(N + 255) / 256, 256, 0, stream>>>(cnt, dinv, N);
    scan1_kernel<<<nb, 256, 0, stream>>>(cnt, excl, bsum, N);
    scan2_kernel<<<1, 256, 0, stream>>>(bsum, bsum2, nb);
    scan3_kernel<<<(N + 255) / 256, 256, 0, stream>>>(excl, bsum2, rowptr, cursor, N, E);
    bucket_kernel<<<2048, 256, 0, stream>>>(src, dst, cursor, esrc, E);

    // layer 1 linear (scaled): Ap = (x @ W1) * dinv  — wave-per-row shfl GEMM
    rowgemm_kernel<<<2048, 256, 0, stream>>>(x_in, W1c, dinv, Ap, N);
    // gather + relu + fused GEMM2 (scaled)
    layer_mid_kernel<<<2048, 256, 0, stream>>>(Ap, esrc, rowptr, dinv, W2c, b1c, A2p, N);
    // gather + bias + softmax + log_softmax
    layer_out_kernel<<<2048, 256, 0, stream>>>(A2p, esrc, rowptr, dinv, b2c, out, N);
}

// Round 7
// 448.067 us; speedup vs baseline: 4.1743x; 1.3127x over previous
//
#include <hip/hip_runtime.h>
#include <math.h>

// ---------------- utility: stream d_in -> d_ws ----------------

__global__ void copy_kernel(const float4* __restrict__ src, float4* __restrict__ dst, int n4) {
    int tid = blockIdx.x * blockDim.x + threadIdx.x;
    int stride = gridDim.x * blockDim.x;
    for (int i = tid; i < n4; i += stride) dst[i] = src[i];
}

// ---------------- CSR build ----------------

__global__ void deg_kernel(const int* __restrict__ dst, int* __restrict__ cnt, int E) {
    int tid = blockIdx.x * blockDim.x + threadIdx.x;
    int stride = gridDim.x * blockDim.x;
    for (int e = tid; e < E; e += stride) atomicAdd(&cnt[dst[e]], 1);
}

__global__ void dinv_kernel(const int* __restrict__ cnt, float* __restrict__ dinv, int N) {
    int tid = blockIdx.x * blockDim.x + threadIdx.x;
    int stride = gridDim.x * blockDim.x;
    for (int v = tid; v < N; v += stride) dinv[v] = rsqrtf((float)(cnt[v] + 1)); // +1 self loop
}

// exclusive scan of cnt, 1024 elements per 256-thread block
__global__ void scan1_kernel(const int* __restrict__ cnt, int* __restrict__ excl,
                             int* __restrict__ bsum, int N) {
    int t = threadIdx.x;
    int base = blockIdx.x * 1024 + t * 4;
    int a0 = base + 0 < N ? cnt[base + 0] : 0;
    int a1 = base + 1 < N ? cnt[base + 1] : 0;
    int a2 = base + 2 < N ? cnt[base + 2] : 0;
    int a3 = base + 3 < N ? cnt[base + 3] : 0;
    int s = a0 + a1 + a2 + a3;
    int lane = t & 63, w = t >> 6;
    int inc = s;
    for (int off = 1; off < 64; off <<= 1) {
        int v = __shfl_up(inc, off);
        if (lane >= off) inc += v;
    }
    __shared__ int wsum[4];
    if (lane == 63) wsum[w] = inc;
    __syncthreads();
    int woff = 0;
    for (int i = 0; i < w; ++i) woff += wsum[i];
    int ex = woff + inc - s;
    if (base + 0 < N) excl[base + 0] = ex;
    if (base + 1 < N) excl[base + 1] = ex + a0;
    if (base + 2 < N) excl[base + 2] = ex + a0 + a1;
    if (base + 3 < N) excl[base + 3] = ex + a0 + a1 + a2;
    if (t == 255) bsum[blockIdx.x] = woff + inc;
}

__global__ void scan2_kernel(const int* __restrict__ bsum, int* __restrict__ bsum2, int nb) {
    int t = threadIdx.x;
    int s = t < nb ? bsum[t] : 0;
    int lane = t & 63, w = t >> 6;
    int inc = s;
    for (int off = 1; off < 64; off <<= 1) {
        int v = __shfl_up(inc, off);
        if (lane >= off) inc += v;
    }
    __shared__ int wsum[4];
    if (lane == 63) wsum[w] = inc;
    __syncthreads();
    int woff = 0;
    for (int i = 0; i < w; ++i) woff += wsum[i];
    if (t < nb) bsum2[t] = woff + inc - s;
}

__global__ void scan3_kernel(const int* __restrict__ excl, const int* __restrict__ bsum2,
                             int* __restrict__ rowptr, int* __restrict__ cursor, int N, int E) {
    int tid = blockIdx.x * blockDim.x + threadIdx.x;
    int stride = gridDim.x * blockDim.x;
    for (int i = tid; i < N; i += stride) {
        int r = excl[i] + bsum2[i >> 10];
        rowptr[i] = r;
        cursor[i] = r;
    }
    if (tid == 0) rowptr[N] = E;
}

__global__ void bucket_kernel(const int* __restrict__ src, const int* __restrict__ dst,
                              int* __restrict__ cursor, int* __restrict__ esrc, int E) {
    int tid = blockIdx.x * blockDim.x + threadIdx.x;
    int stride = gridDim.x * blockDim.x;
    for (int e = tid; e < E; e += stride) {
        int p = atomicAdd(&cursor[dst[e]], 1);
        esrc[p] = src[e];
    }
}

// ---------------- layer kernels ----------------

// Ap[N,64] = (X[N,128] @ W1) * dinv[row].
// Wave per row. W1 column held in 128 registers per lane (lane = out col).
// x row staged in per-wave LDS buffer; inner loop reads it at wave-uniform
// addresses (LDS broadcast) -> 33 LDS ops/row instead of 256 (shfl version).
__launch_bounds__(256, 2)
__global__ void rowgemm_kernel(const float* __restrict__ X, const float* __restrict__ W,
                               const float* __restrict__ dinv, float* __restrict__ Ap, int N) {
    __shared__ float xbuf[4][128];
    int lane = threadIdx.x & 63;
    int wv = threadIdx.x >> 6;
    float w[128];
#pragma unroll
    for (int k = 0; k < 128; ++k) w[k] = W[k * 64 + lane];   // coalesced per k
    int gtid = blockIdx.x * blockDim.x + threadIdx.x;
    int wave = gtid >> 6;
    int nw = (gridDim.x * blockDim.x) >> 6;
    const float4* xb4 = (const float4*)xbuf[wv];
    for (int v = wave; v < N; v += nw) {
        float2 x2 = *(const float2*)(X + (size_t)v * 128 + lane * 2);
        *(float2*)&xbuf[wv][lane * 2] = x2;
        asm volatile("s_waitcnt lgkmcnt(0)" ::: "memory");
        float acc = 0.f;
#pragma unroll
        for (int k4 = 0; k4 < 32; ++k4) {
            float4 xv = xb4[k4];               // wave-uniform broadcast read
            acc += xv.x * w[4 * k4 + 0] + xv.y * w[4 * k4 + 1]
                 + xv.z * w[4 * k4 + 2] + xv.w * w[4 * k4 + 3];
        }
        Ap[(size_t)v * 64 + lane] = acc * dinv[v];
        asm volatile("s_waitcnt lgkmcnt(0)" ::: "memory");   // reads done before next overwrite
    }
}

// Wave per node: gather Ap rows via CSR, h = relu(dinv*(sum + Ap[v]*dinv) + b1),
// then fused GEMM2 with W2 column in 64 registers (lane = out col), h staged in
// per-wave LDS buffer read at uniform addresses.
__launch_bounds__(256, 2)
__global__ void layer_mid_kernel(const float* __restrict__ Ap, const int* __restrict__ esrc,
                                 const int* __restrict__ rowptr, const float* __restrict__ dinv,
                                 const float* __restrict__ W2, const float* __restrict__ b1,
                                 float* __restrict__ A2p, int N) {
    __shared__ float hbuf[4][64];
    int lane = threadIdx.x & 63;
    int wv = threadIdx.x >> 6;
    int cidx = lane < 40 ? lane : 0;
    float w2[64];
#pragma unroll
    for (int k = 0; k < 64; ++k) w2[k] = W2[k * 40 + cidx];
    float bias = b1[lane];
    int gtid = blockIdx.x * blockDim.x + threadIdx.x;
    int wave = gtid >> 6;
    int nw = (gridDim.x * blockDim.x) >> 6;
    const float4* hb4 = (const float4*)hbuf[wv];
    for (int v = wave; v < N; v += nw) {
        int i0 = rowptr[v], i1 = rowptr[v + 1];
        float acc = 0.f;
        for (int base = i0; base < i1; base += 64) {
            int n = min(64, i1 - base);
            int el = (lane < n) ? esrc[base + lane] : 0;
            int j = 0;
            for (; j + 4 <= n; j += 4) {
                int s0 = __shfl(el, j), s1 = __shfl(el, j + 1);
                int s2 = __shfl(el, j + 2), s3 = __shfl(el, j + 3);
                float f0 = Ap[(size_t)s0 * 64 + lane];
                float f1 = Ap[(size_t)s1 * 64 + lane];
                float f2 = Ap[(size_t)s2 * 64 + lane];
                float f3 = Ap[(size_t)s3 * 64 + lane];
                acc += f0; acc += f1; acc += f2; acc += f3;
            }
            for (; j < n; ++j) {
                int s0 = __shfl(el, j);
                acc += Ap[(size_t)s0 * 64 + lane];
            }
        }
        float dv = dinv[v];
        float h = dv * (acc + Ap[(size_t)v * 64 + lane] * dv) + bias;
        h = h > 0.f ? h : 0.f;
        hbuf[wv][lane] = h;
        asm volatile("s_waitcnt lgkmcnt(0)" ::: "memory");
        float a2 = 0.f;
#pragma unroll
        for (int k4 = 0; k4 < 16; ++k4) {
            float4 hv = hb4[k4];               // wave-uniform broadcast read
            a2 += hv.x * w2[4 * k4 + 0] + hv.y * w2[4 * k4 + 1]
                + hv.z * w2[4 * k4 + 2] + hv.w * w2[4 * k4 + 3];
        }
        if (lane < 40) A2p[(size_t)v * 40 + lane] = a2 * dv;
        asm volatile("s_waitcnt lgkmcnt(0)" ::: "memory");
    }
}

// Wave per node: gather A2p rows, z = dinv*(sum + A2p[v]*dinv) + b2,
// out = log_softmax(softmax(z)) over 40 cols.
__global__ void layer_out_kernel(const float* __restrict__ A2p, const int* __restrict__ esrc,
                                 const int* __restrict__ rowptr, const float* __restrict__ dinv,
                                 const float* __restrict__ b2, float* __restrict__ out, int N) {
    int gtid = blockIdx.x * blockDim.x + threadIdx.x;
    int wave = gtid >> 6, lane = threadIdx.x & 63;
    int nw = (gridDim.x * blockDim.x) >> 6;
    for (int v = wave; v < N; v += nw) {
        int i0 = rowptr[v], i1 = rowptr[v + 1];
        bool act = lane < 40;
        float acc = 0.f;
        for (int base = i0; base < i1; base += 64) {
            int n = min(64, i1 - base);
            int el = (lane < n) ? esrc[base + lane] : 0;
            int j = 0;
            for (; j + 4 <= n; j += 4) {
                int s0 = __shfl(el, j), s1 = __shfl(el, j + 1);
                int s2 = __shfl(el, j + 2), s3 = __shfl(el, j + 3);
                if (act) {
                    float f0 = A2p[(size_t)s0 * 40 + lane];
                    float f1 = A2p[(size_t)s1 * 40 + lane];
                    float f2 = A2p[(size_t)s2 * 40 + lane];
                    float f3 = A2p[(size_t)s3 * 40 + lane];
                    acc += f0; acc += f1; acc += f2; acc += f3;
                }
            }
            for (; j < n; ++j) {
                int s0 = __shfl(el, j);
                if (act) acc += A2p[(size_t)s0 * 40 + lane];
            }
        }
        float dv = dinv[v];
        float z = act ? dv * (acc + A2p[(size_t)v * 40 + lane] * dv) + b2[lane] : -INFINITY;
        float m = z;
        for (int off = 32; off; off >>= 1) m = fmaxf(m, __shfl_xor(m, off));
        float e = act ? expf(z - m) : 0.f;
        float s = e;
        for (int off = 32; off; off >>= 1) s += __shfl_xor(s, off);
        float p = e / s;
        float m2 = act ? p : -INFINITY;
        for (int off = 32; off; off >>= 1) m2 = fmaxf(m2, __shfl_xor(m2, off));
        float e2 = act ? expf(p - m2) : 0.f;
        float s2 = e2;
        for (int off = 32; off; off >>= 1) s2 += __shfl_xor(s2, off);
        if (act) out[(size_t)v * 40 + lane] = (p - m2) - logf(s2);
    }
}

// ---------------- launch ----------------

extern "C" void kernel_launch(void* const* d_in, const int* in_sizes, int n_in,
                              void* d_out, int out_size, void* d_ws, size_t ws_size,
                              hipStream_t stream) {
    const float* x_in  = (const float*)d_in[0];
    const int*   ei    = (const int*)d_in[1];
    const float* W1_in = (const float*)d_in[2];
    const float* b1_in = (const float*)d_in[3];
    const float* W2_in = (const float*)d_in[4];
    const float* b2_in = (const float*)d_in[5];
    float* out = (float*)d_out;

    int N = in_sizes[0] / 128;
    int E = in_sizes[1] / 2;
    const int* src = ei;
    const int* dst = ei + E;

    int nb = (N + 1023) / 1024;

    char* ws = (char*)d_ws;
    size_t o = 0;
    auto alloc = [&](size_t bytes) { void* p = ws + o; o += (bytes + 255) & ~(size_t)255; return p; };
    int*   cnt    = (int*)alloc((size_t)N * 4);
    int*   cursor = (int*)alloc((size_t)N * 4);
    float* dinv   = (float*)alloc((size_t)N * 4);
    int*   excl   = (int*)alloc((size_t)N * 4);
    int*   rowptr = (int*)alloc(((size_t)N + 1) * 4);
    int*   bsum   = (int*)alloc(1024);
    int*   bsum2  = (int*)alloc(1024);
    int*   esrc   = (int*)alloc((size_t)E * 4);
    float* Ap     = (float*)alloc((size_t)N * 64 * 4);
    float* A2p    = (float*)alloc((size_t)N * 40 * 4);
    float* W1c = (float*)alloc(128 * 64 * 4);
    float* W2c = (float*)alloc(64 * 40 * 4);
    float* b1c = (float*)alloc(64 * 4);
    float* b2c = (float*)alloc(40 * 4);

    // stage small fp32 params into workspace
    copy_kernel<<<8, 256, 0, stream>>>((const float4*)W1_in, (float4*)W1c, 128 * 64 / 4);
    copy_kernel<<<4, 256, 0, stream>>>((const float4*)W2_in, (float4*)W2c, 64 * 40 / 4);
    copy_kernel<<<1, 64, 0, stream>>>((const float4*)b1_in, (float4*)b1c, 16);
    copy_kernel<<<1, 64, 0, stream>>>((const float4*)b2_in, (float4*)b2c, 10);

    // CSR build + degree norm
    hipMemsetAsync(cnt, 0, (size_t)N * 4, stream);
    deg_kernel<<<1024, 256, 0, stream>>>(dst, cnt, E);
    dinv_kernel<<<(N + 255) / 256, 256, 0, stream>>>(cnt, dinv, N);
    scan1_kernel<<<nb, 256, 0, stream>>>(cnt, excl, bsum, N);
    scan2_kernel<<<1, 256, 0, stream>>>(bsum, bsum2, nb);
    scan3_kernel<<<(N + 255) / 256, 256, 0, stream>>>(excl, bsum2, rowptr, cursor, N, E);
    bucket_kernel<<<2048, 256, 0, stream>>>(src, dst, cursor, esrc, E);

    // layer 1 linear (scaled): Ap = (x @ W1) * dinv
    rowgemm_kernel<<<1024, 256, 0, stream>>>(x_in, W1c, dinv, Ap, N);
    // gather + relu + fused GEMM2 (scaled)
    layer_mid_kernel<<<2048, 256, 0, stream>>>(Ap, esrc, rowptr, dinv, W2c, b1c, A2p, N);
    // gather + bias + softmax + log_softmax
    layer_out_kernel<<<2048, 256, 0, stream>>>(A2p, esrc, rowptr, dinv, b2c, out, N);
}